// Round 3
// baseline (580.606 us; speedup 1.0000x reference)
//
#include <hip/hip_runtime.h>
#include <hip/hip_bf16.h>
#include <cstdint>

// Problem constants
#define BATCH 32
#define CIN   256
#define COUT  256
#define HW    56
#define NEXP  8
#define HP    58           // padded spatial
#define KTOT  2304         // CIN*9

typedef __bf16 bf16x8 __attribute__((ext_vector_type(8)));
typedef float  f32x4  __attribute__((ext_vector_type(4)));
typedef unsigned short u16x8 __attribute__((ext_vector_type(8)));

static __device__ __forceinline__ unsigned short f32_to_bf16(float f) {
    uint32_t u = __builtin_bit_cast(uint32_t, f);
    return (unsigned short)((u + 0x7FFFu + ((u >> 16) & 1u)) >> 16);
}

// ---- x fp32 [b][i][56][56] -> xTp bf16 [b][58][58][i] (zero halo) + GAP row-sums ----
__global__ void transpose_kernel(const float* __restrict__ x, unsigned short* __restrict__ xtp,
                                 float* __restrict__ gap) {
    int hp = blockIdx.x;           // 0..57 padded row
    int ib = blockIdx.y;           // i-block of 32
    int b  = blockIdx.z;
    int t  = threadIdx.x;
    __shared__ float tile[32][57];
    bool in_h = (hp >= 1 && hp <= HW);
    if (in_h) {
        const float* src = x + (((size_t)b * CIN + ib * 32) * HW + (hp - 1)) * HW;
        for (int idx = t; idx < 32 * HW; idx += 256) {
            int il = idx / HW, w = idx - il * HW;
            tile[il][w] = src[(size_t)il * (HW * HW) + w];
        }
    }
    __syncthreads();
    unsigned short* dst = xtp + (((size_t)b * HP + hp) * HP) * CIN + ib * 32;
    for (int idx = t; idx < HP * 32; idx += 256) {
        int wp = idx >> 5, il = idx & 31;
        float v = 0.f;
        if (in_h && wp >= 1 && wp <= HW) v = tile[il][wp - 1];
        dst[(size_t)wp * CIN + il] = f32_to_bf16(v);
    }
    if (in_h) {
        int c = t >> 3, j0 = t & 7;
        float s = 0.f;
        for (int j = j0; j < HW; j += 8) s += tile[c][j];
        s += __shfl_down(s, 4, 8);
        s += __shfl_down(s, 2, 8);
        s += __shfl_down(s, 1, 8);
        if (j0 == 0) atomicAdd(&gap[b * CIN + ib * 32 + c], s);
    }
}

// ---- routing[b][e] = sigmoid(gapsum[b]·fc_w[e]/3136 + fc_b[e]) ----
__global__ void routing_kernel(const float* __restrict__ gap, const float* __restrict__ fcw,
                               const float* __restrict__ fcb, float* __restrict__ rout) {
    int t = threadIdx.x;
    int b = t >> 3, e = t & 7;
    const float* g = gap + b * CIN;
    const float* w = fcw + e * CIN;
    float z = 0.f;
    for (int c = 0; c < CIN; ++c) z += g[c] * w[c];
    z = z * (1.0f / 3136.0f) + fcb[e];
    rout[b * NEXP + e] = 1.f / (1.f + expf(-z));
}

// ---- cmb2[b][o][ib][r][il] = sum_e rout[b][e] * kw[e][o][ib*32+il][r]  (bf16) ----
__global__ void combine_kernel(const float* __restrict__ kw, const float* __restrict__ rout,
                               unsigned short* __restrict__ cmb) {
    int o = blockIdx.x;
    int t = threadIdx.x;           // = input channel i
    __shared__ float rs[BATCH][NEXP];
    rs[t >> 3][t & 7] = rout[t];
    __syncthreads();
    float kv[NEXP][9];
    #pragma unroll
    for (int e = 0; e < NEXP; ++e) {
        const float* p = kw + (((size_t)e * COUT + o) * CIN + t) * 9;
        #pragma unroll
        for (int r = 0; r < 9; ++r) kv[e][r] = p[r];
    }
    int ib = t >> 5, il = t & 31;
    for (int b = 0; b < BATCH; ++b) {
        unsigned short* dst = cmb + ((((size_t)b * COUT + o) * 8 + ib) * 9) * 32 + il;
        #pragma unroll
        for (int r = 0; r < 9; ++r) {
            float s = 0.f;
            #pragma unroll
            for (int e = 0; e < NEXP; ++e) s += rs[b][e] * kv[e][r];
            dst[r * 32] = f32_to_bf16(s);
        }
    }
}

// ---- conv: implicit GEMM. Block 256o x 112px, 4 waves (64o each, 4m x 7n frags).
// B-window (16h x 10w x 32i per ib) staged to LDS via global_load_lds, double-buffered,
// bank-swizzled via pre-swizzled SOURCE address. A-frags direct global->reg.
#define WBYTES 10240

__global__ __launch_bounds__(256, 2)
void conv_kernel(const unsigned short* __restrict__ xtp, const unsigned short* __restrict__ cmb,
                 float* __restrict__ out) {
    __shared__ __align__(16) char lds[2 * WBYTES];
    int t = threadIdx.x;
    int wave = t >> 6, l = t & 63, lr = l & 15, lk = l >> 4;

    // XCD-chunked bijective swizzle: 896 blocks = 8 XCDs x 112
    int bid = blockIdx.x;
    int wg  = (bid & 7) * 112 + (bid >> 3);
    int b   = wg / 28, pt = wg - b * 28;
    int ty = pt / 7, tx = pt - ty * 7;
    int oh0 = ty * 14, ow0 = tx * 8;
    int o0  = wave * 64;

    const unsigned short* xb = xtp + (size_t)b * (HP * HP * CIN);

    // window stage: 640 chunks of 16B; group j (64 chunks) -> wave j%4; lane l -> chunk j*64+l
    int goff[3];
    int ng = (wave < 2) ? 3 : 2;
    #pragma unroll
    for (int k = 0; k < 3; ++k) {
        int j = wave + 4 * k;
        int c = j * 64 + l;
        int pos = c >> 2, q = c & 3;
        int qs = q ^ ((pos >> 1) & 3);          // bank swizzle in SOURCE
        int hh = pos / 10, ww = pos - hh * 10;
        goff[k] = ((oh0 + hh) * HP + (ow0 + ww)) * CIN + qs * 8;
    }

    // A fragment row pointers (cmb2 layout [b][o][ib*288 + r*32 + il])
    const unsigned short* ap[4];
    #pragma unroll
    for (int m = 0; m < 4; ++m)
        ap[m] = cmb + (size_t)(b * COUT + o0 + m * 16 + lr) * KTOT + lk * 8;

    int pos0[7];
    #pragma unroll
    for (int nt = 0; nt < 7; ++nt)
        pos0[nt] = (nt * 2 + (lr >> 3)) * 10 + (lr & 7);

    f32x4 acc[4][7];
    #pragma unroll
    for (int m = 0; m < 4; ++m)
        #pragma unroll
        for (int nt = 0; nt < 7; ++nt) acc[m][nt] = (f32x4){0.f, 0.f, 0.f, 0.f};

#define STAGE(ibx, bufx)                                                              \
    do {                                                                              \
        for (int k = 0; k < ng; ++k)                                                  \
            __builtin_amdgcn_global_load_lds(                                         \
                (const __attribute__((address_space(1))) void*)(xb + goff[k] + (ibx) * 32), \
                (__attribute__((address_space(3))) void*)(lds + (bufx) * WBYTES + (wave + 4 * k) * 1024), \
                16, 0, 0);                                                            \
    } while (0)

    STAGE(0, 0);
    __syncthreads();

    for (int ib = 0; ib < 8; ++ib) {
        if (ib < 7) STAGE(ib + 1, (ib + 1) & 1);
        const char* cur = lds + (ib & 1) * WBYTES;
        #pragma unroll
        for (int r = 0; r < 9; ++r) {
            const int dh = r / 3, dw = r - (r / 3) * 3;
            bf16x8 a[4];
            #pragma unroll
            for (int m = 0; m < 4; ++m)
                a[m] = __builtin_bit_cast(bf16x8,
                        *reinterpret_cast<const u16x8*>(ap[m] + ib * 288 + r * 32));
            #pragma unroll
            for (int nt = 0; nt < 7; ++nt) {
                int pos  = pos0[nt] + dh * 10 + dw;
                int boff = (pos * 4 + (lk ^ ((pos >> 1) & 3))) * 16;
                bf16x8 bq = *reinterpret_cast<const bf16x8*>(cur + boff);
                #pragma unroll
                for (int m = 0; m < 4; ++m)
                    acc[m][nt] = __builtin_amdgcn_mfma_f32_16x16x32_bf16(a[m], bq, acc[m][nt], 0, 0, 0);
            }
        }
        __syncthreads();   // drains vmcnt (stage ib+1) + lgkm; buffers swap safely
    }

    // epilogue: D col = lane&15 (pixel), row = (lane>>4)*4 + reg (o)
    #pragma unroll
    for (int m = 0; m < 4; ++m) {
        #pragma unroll
        for (int nt = 0; nt < 7; ++nt) {
            int oh = oh0 + nt * 2 + (lr >> 3), ow = ow0 + (lr & 7);
            float* op = out + ((size_t)(b * COUT + o0 + m * 16 + lk * 4)) * (HW * HW)
                        + oh * HW + ow;
            #pragma unroll
            for (int reg = 0; reg < 4; ++reg)
                op[(size_t)reg * (HW * HW)] = acc[m][nt][reg];
        }
    }
#undef STAGE
}

extern "C" void kernel_launch(void* const* d_in, const int* in_sizes, int n_in,
                              void* d_out, int out_size, void* d_ws, size_t ws_size,
                              hipStream_t stream) {
    const float* x   = (const float*)d_in[0];
    const float* kw  = (const float*)d_in[1];
    const float* fcw = (const float*)d_in[2];
    const float* fcb = (const float*)d_in[3];
    float* out = (float*)d_out;

    char* ws = (char*)d_ws;
    float* gap  = (float*)(ws + 0);                        //  32768 B
    float* rout = (float*)(ws + 32768);                    //   1024 B
    unsigned short* cmb = (unsigned short*)(ws + 33792);   // 37748736 B
    unsigned short* xtp = (unsigned short*)(ws + 33792 + 37748736); // 55107584 B

    hipMemsetAsync(gap, 0, BATCH * CIN * sizeof(float), stream);
    transpose_kernel<<<dim3(HP, 8, BATCH), 256, 0, stream>>>(x, xtp, gap);
    routing_kernel<<<1, 256, 0, stream>>>(gap, fcw, fcb, rout);
    combine_kernel<<<COUT, 256, 0, stream>>>(kw, rout, cmb);
    conv_kernel<<<dim3(896), 256, 0, stream>>>(xtp, cmb, out);
}

// Round 4
// 328.529 us; speedup vs baseline: 1.7673x; 1.7673x over previous
//
#include <hip/hip_runtime.h>
#include <hip/hip_bf16.h>
#include <cstdint>

#define BATCH 32
#define CIN   256
#define COUT  256
#define HW    56
#define NEXP  8
#define HP    58

typedef __bf16 bf16x8 __attribute__((ext_vector_type(8)));
typedef float  f32x16 __attribute__((ext_vector_type(16)));
typedef unsigned short u16x8 __attribute__((ext_vector_type(8)));

static __device__ __forceinline__ unsigned short f32_to_bf16(float f) {
    uint32_t u = __builtin_bit_cast(uint32_t, f);
    return (unsigned short)((u + 0x7FFFu + ((u >> 16) & 1u)) >> 16);
}

// ---- x fp32 [b][i][56][56] -> xTp bf16 [b][58][58][i] (zero halo) + GAP row-sums ----
__global__ void transpose_kernel(const float* __restrict__ x, unsigned short* __restrict__ xtp,
                                 float* __restrict__ gap) {
    int hp = blockIdx.x;
    int ib = blockIdx.y;
    int b  = blockIdx.z;
    int t  = threadIdx.x;
    __shared__ float tile[32][57];
    bool in_h = (hp >= 1 && hp <= HW);
    if (in_h) {
        const float* src = x + (((size_t)b * CIN + ib * 32) * HW + (hp - 1)) * HW;
        for (int idx = t; idx < 32 * HW; idx += 256) {
            int il = idx / HW, w = idx - il * HW;
            tile[il][w] = src[(size_t)il * (HW * HW) + w];
        }
    }
    __syncthreads();
    unsigned short* dst = xtp + (((size_t)b * HP + hp) * HP) * CIN + ib * 32;
    for (int idx = t; idx < HP * 32; idx += 256) {
        int wp = idx >> 5, il = idx & 31;
        float v = 0.f;
        if (in_h && wp >= 1 && wp <= HW) v = tile[il][wp - 1];
        dst[(size_t)wp * CIN + il] = f32_to_bf16(v);
    }
    if (in_h) {
        int c = t >> 3, j0 = t & 7;
        float s = 0.f;
        for (int j = j0; j < HW; j += 8) s += tile[c][j];
        s += __shfl_down(s, 4, 8);
        s += __shfl_down(s, 2, 8);
        s += __shfl_down(s, 1, 8);
        if (j0 == 0) atomicAdd(&gap[b * CIN + ib * 32 + c], s);
    }
}

// ---- routing[b][e] = sigmoid(gapsum[b]·fc_w[e]/3136 + fc_b[e]) ----
__global__ void routing_kernel(const float* __restrict__ gap, const float* __restrict__ fcw,
                               const float* __restrict__ fcb, float* __restrict__ rout) {
    int t = threadIdx.x;
    int b = t >> 3, e = t & 7;
    const float* g = gap + b * CIN;
    const float* w = fcw + e * CIN;
    float z = 0.f;
    for (int c = 0; c < CIN; ++c) z += g[c] * w[c];
    z = z * (1.0f / 3136.0f) + fcb[e];
    rout[b * NEXP + e] = 1.f / (1.f + expf(-z));
}

// ---- cmb[b][ib][r][o][i32 (16B-slot-swizzled)] ----
// slot layout within a 64B row for o: source chunk q stored at slot q ^ ((o>>1)&3)
__global__ void combine_kernel(const float* __restrict__ kw, const float* __restrict__ rout,
                               unsigned short* __restrict__ cmb) {
    int o = blockIdx.x;
    int t = threadIdx.x;             // channel i
    __shared__ float rs[BATCH][NEXP];
    rs[t >> 3][t & 7] = rout[t];
    __syncthreads();
    float kv[NEXP][9];
    #pragma unroll
    for (int e = 0; e < NEXP; ++e) {
        const float* p = kw + (((size_t)e * COUT + o) * CIN + t) * 9;
        #pragma unroll
        for (int r = 0; r < 9; ++r) kv[e][r] = p[r];
    }
    int ib = t >> 5, il = t & 31;
    int q = il >> 3, i8 = il & 7;
    int slot = q ^ ((o >> 1) & 3);
    for (int b = 0; b < BATCH; ++b) {
        #pragma unroll
        for (int r = 0; r < 9; ++r) {
            float s = 0.f;
            #pragma unroll
            for (int e = 0; e < NEXP; ++e) s += rs[b][e] * kv[e][r];
            cmb[(size_t)(b * 72 + ib * 9 + r) * 8192 + o * 32 + slot * 8 + i8] = f32_to_bf16(s);
        }
    }
}

// ---- conv: block 256o x 64px (8x8), 4 waves (64o each), 32x32x16 MFMA ----
// LDS: A dbuf 2x16KB (256 rows x 64B, slot-swizzled) + window dbuf 2x8KB (128 pos x 64B)
#define LDS_A0 0
#define LDS_A1 16384
#define LDS_W0 32768
#define LDS_W1 40960

__global__ __launch_bounds__(256)
void conv_kernel(const unsigned short* __restrict__ xtp, const unsigned short* __restrict__ cmb,
                 float* __restrict__ out) {
    __shared__ __align__(16) char lds[49152];
    const int t = threadIdx.x, wave = t >> 6, l = t & 63;
    const int l31 = l & 31, lhi = l >> 5;

    // bijective XCD-chunked swizzle: 1568 = 8 x 196
    int bid = blockIdx.x;
    int wg  = (bid & 7) * 196 + (bid >> 3);
    int b   = wg / 49, pt = wg - b * 49;
    int ty = pt / 7, tx = pt - ty * 7;
    int oh0 = ty * 8, ow0 = tx * 8;

    const char* xb = (const char*)xtp + (size_t)b * (HP * HP * CIN * 2);
    const char* cb = (const char*)cmb + (size_t)b * (72 * 16384);

    // per-lane window source offsets (chunk c = (wave+4j)*64 + l; LDS byte = c*16)
    int wsrc[2];
    #pragma unroll
    for (int j = 0; j < 2; ++j) {
        int c = (wave + 4 * j) * 64 + l;
        int cc = (c < 400) ? c : 0;            // clamp padding chunks in-bounds
        int pos = cc >> 2, q = cc & 3;
        int qp = q ^ ((pos >> 1) & 3);         // bank swizzle baked into SOURCE
        int hh = pos / 10, ww = pos - hh * 10;
        wsrc[j] = ((oh0 + hh) * HP + (ow0 + ww)) * 512 + qp * 16;
    }

#define STAGE_A(sidx, buf)                                                                      \
    { _Pragma("unroll")                                                                         \
      for (int j = 0; j < 4; ++j)                                                               \
        __builtin_amdgcn_global_load_lds(                                                       \
            (const __attribute__((address_space(1))) void*)(cb + (size_t)(sidx) * 16384         \
                                                            + (wave * 4 + j) * 1024 + l * 16),  \
            (__attribute__((address_space(3))) void*)(lds + (buf) + (wave * 4 + j) * 1024),     \
            16, 0, 0); }

#define STAGE_W(ibx, buf)                                                                       \
    { _Pragma("unroll")                                                                         \
      for (int j = 0; j < 2; ++j)                                                               \
        __builtin_amdgcn_global_load_lds(                                                       \
            (const __attribute__((address_space(1))) void*)(xb + wsrc[j] + (ibx) * 64),         \
            (__attribute__((address_space(3))) void*)(lds + (buf) + (wave + 4 * j) * 1024),     \
            16, 0, 0); }

    f32x16 acc[2][2];
    #pragma unroll
    for (int m = 0; m < 2; ++m)
        #pragma unroll
        for (int n = 0; n < 2; ++n)
            #pragma unroll
            for (int k = 0; k < 16; ++k) acc[m][n][k] = 0.f;

    STAGE_A(0, LDS_A0);
    STAGE_W(0, LDS_W0);
    __syncthreads();

    for (int ib = 0; ib < 8; ++ib) {
        const char* curw = lds + ((ib & 1) ? LDS_W1 : LDS_W0);
        #pragma unroll
        for (int r = 0; r < 9; ++r) {
            const int s = ib * 9 + r;
            const char* cura = lds + ((s & 1) ? LDS_A1 : LDS_A0);
            // prefetch next K-step into the other buffers
            if (r < 8) {
                STAGE_A(s + 1, (s & 1) ? LDS_A0 : LDS_A1);
            } else if (ib < 7) {
                STAGE_A(s + 1, (s & 1) ? LDS_A0 : LDS_A1);
                STAGE_W(ib + 1, (ib & 1) ? LDS_W0 : LDS_W1);
            }
            const int dh = r / 3, dw = r - (r / 3) * 3;
            bf16x8 af[2][2], bf[2][2];
            #pragma unroll
            for (int m = 0; m < 2; ++m)
                #pragma unroll
                for (int kh = 0; kh < 2; ++kh) {
                    int row  = wave * 64 + m * 32 + l31;
                    int slot = (kh * 2 + lhi) ^ ((l31 >> 1) & 3);
                    af[m][kh] = *(const bf16x8*)(cura + row * 64 + slot * 16);
                }
            #pragma unroll
            for (int n = 0; n < 2; ++n)
                #pragma unroll
                for (int kh = 0; kh < 2; ++kh) {
                    int pos  = (n * 4 + (l31 >> 3) + dh) * 10 + (l31 & 7) + dw;
                    int slot = (kh * 2 + lhi) ^ ((pos >> 1) & 3);
                    bf[n][kh] = *(const bf16x8*)(curw + pos * 64 + slot * 16);
                }
            #pragma unroll
            for (int m = 0; m < 2; ++m)
                #pragma unroll
                for (int n = 0; n < 2; ++n)
                    #pragma unroll
                    for (int kh = 0; kh < 2; ++kh)
                        acc[m][n] = __builtin_amdgcn_mfma_f32_32x32x16_bf16(
                            af[m][kh], bf[n][kh], acc[m][n], 0, 0, 0);
            __syncthreads();
        }
    }

    // epilogue: D col = lane&31 (pixel), row = (reg&3)+8*(reg>>2)+4*(lane>>5) (o)
    #pragma unroll
    for (int m = 0; m < 2; ++m)
        #pragma unroll
        for (int n = 0; n < 2; ++n) {
            int py = l31 >> 3, px = l31 & 7;
            int oh = oh0 + n * 4 + py, ow = ow0 + px;
            #pragma unroll
            for (int reg = 0; reg < 16; ++reg) {
                int row = (reg & 3) + 8 * (reg >> 2) + 4 * lhi;
                int o   = wave * 64 + m * 32 + row;
                out[(((size_t)b * COUT + o) * HW + oh) * HW + ow] = acc[m][n][reg];
            }
        }
#undef STAGE_A
#undef STAGE_W
}

extern "C" void kernel_launch(void* const* d_in, const int* in_sizes, int n_in,
                              void* d_out, int out_size, void* d_ws, size_t ws_size,
                              hipStream_t stream) {
    const float* x   = (const float*)d_in[0];
    const float* kw  = (const float*)d_in[1];
    const float* fcw = (const float*)d_in[2];
    const float* fcb = (const float*)d_in[3];
    float* out = (float*)d_out;

    char* ws = (char*)d_ws;
    float* gap  = (float*)(ws + 0);                        //  32768 B
    float* rout = (float*)(ws + 32768);                    //   1024 B
    unsigned short* cmb = (unsigned short*)(ws + 33792);   // 37748736 B
    unsigned short* xtp = (unsigned short*)(ws + 33792 + 37748736); // 55107584 B

    hipMemsetAsync(gap, 0, BATCH * CIN * sizeof(float), stream);
    transpose_kernel<<<dim3(HP, 8, BATCH), 256, 0, stream>>>(x, xtp, gap);
    routing_kernel<<<1, 256, 0, stream>>>(gap, fcw, fcb, rout);
    combine_kernel<<<COUT, 256, 0, stream>>>(kw, rout, cmb);
    conv_kernel<<<dim3(1568), 256, 0, stream>>>(xtp, cmb, out);
}